// Round 3
// baseline (781.256 us; speedup 1.0000x reference)
//
#include <hip/hip_runtime.h>
#include <hip/hip_bf16.h>
#include <stdint.h>

#define NTILES 4
#define DMODEL 1024
#define DFF    4096
#define NTOK   16384
#define GY     20

typedef __bf16 bf16x8 __attribute__((ext_vector_type(8)));
typedef float  f32x4  __attribute__((ext_vector_type(4)));

__device__ __forceinline__ uint16_t f2bf(float f) {
    union { float f; uint32_t u; } v; v.f = f;
    uint32_t u = v.u;
    uint32_t r = (u + 0x7fffu + ((u >> 16) & 1u)) >> 16;
    return (uint16_t)r;
}

#define STG(gptr, ldsptr) __builtin_amdgcn_global_load_lds( \
    (__attribute__((address_space(1))) void*)(gptr), \
    (__attribute__((address_space(3))) void*)(ldsptr), 16, 0, 0)

// ---------------- fused Wup fp32->bf16 convert + signature partial sums ----------------
__global__ void k_convup(const float* __restrict__ Wup, uint16_t* __restrict__ wupb,
                         double* __restrict__ partial) {
    int e = blockIdx.y, fb = blockIdx.x, tid = threadIdx.x;
    const float* src = Wup + (size_t)e * DFF * DMODEL + (size_t)fb * 64 * DMODEL + tid * 4;
    uint16_t*    dst = wupb + (size_t)e * DFF * DMODEL + (size_t)fb * 64 * DMODEL + tid * 4;
    double s0 = 0, s1 = 0, s2 = 0, s3 = 0;
    for (int i = 0; i < 64; ++i) {
        float4 v = *(const float4*)(src + (size_t)i * DMODEL);
        ushort4 h;
        h.x = f2bf(v.x); h.y = f2bf(v.y); h.z = f2bf(v.z); h.w = f2bf(v.w);
        *(ushort4*)(dst + (size_t)i * DMODEL) = h;
        s0 += v.x; s1 += v.y; s2 += v.z; s3 += v.w;
    }
    int c = tid * 4;
    double* p = partial + ((size_t)e * DMODEL + c) * 64 + fb;
    p[0 * 64] = s0; p[1 * 64] = s1; p[2 * 64] = s2; p[3 * 64] = s3;
}

// signature finalize + zero expert counts (runs before k_route)
__global__ void k_sig_final(const double* __restrict__ partial, float* __restrict__ sig,
                            int* __restrict__ counts) {
    int idx = blockIdx.x * 256 + threadIdx.x;   // 0..4095
    if (blockIdx.x == 0 && threadIdx.x < NTILES) counts[threadIdx.x] = 0;
    double s = 0.0;
    for (int fb = 0; fb < 64; ++fb) s += partial[(size_t)idx * 64 + fb];
    sig[idx] = (s > 0.0) ? 1.0f : ((s < 0.0) ? -1.0f : 0.0f);
}

// ---------------- routing: scores, argmax, gate, xb (bf16 copy), buckets ----------------
__global__ void __launch_bounds__(256) k_route(const float* __restrict__ x,
                                               const float* __restrict__ sig,
                                               uint16_t* __restrict__ xb,
                                               float* __restrict__ gate_out,
                                               int* __restrict__ counts,
                                               int* __restrict__ perm) {
    __shared__ float sl[NTILES * DMODEL];
    for (int i = threadIdx.x; i < NTILES * DMODEL; i += 256) sl[i] = sig[i];
    __syncthreads();
    int wave = threadIdx.x >> 6, lane = threadIdx.x & 63;
    int tok = blockIdx.x * 4 + wave;
    const float* xr = x + (size_t)tok * DMODEL;
    float sc[NTILES] = {0.f, 0.f, 0.f, 0.f};
    for (int q = 0; q < 4; ++q) {
        int c = q * 256 + lane * 4;
        float4 xv = *(const float4*)(xr + c);
        #pragma unroll
        for (int t = 0; t < NTILES; ++t) {
            const float* st = sl + t * DMODEL + c;
            sc[t] += xv.x * st[0] + xv.y * st[1] + xv.z * st[2] + xv.w * st[3];
        }
        ushort4 h;
        h.x = f2bf(xv.x); h.y = f2bf(xv.y); h.z = f2bf(xv.z); h.w = f2bf(xv.w);
        *(ushort4*)(xb + (size_t)tok * DMODEL + c) = h;
    }
    #pragma unroll
    for (int t = 0; t < NTILES; ++t)
        for (int off = 32; off; off >>= 1) sc[t] += __shfl_xor(sc[t], off);
    int w = 0; float best = sc[0];
    if (sc[1] > best) { best = sc[1]; w = 1; }
    if (sc[2] > best) { best = sc[2]; w = 2; }
    if (sc[3] > best) { best = sc[3]; w = 3; }
    if (lane < NTILES) gate_out[(size_t)tok * NTILES + lane] = (lane == w) ? 1.0f : 0.0f;
    if (lane == 0) {
        int pos = atomicAdd(&counts[w], 1);
        perm[w * NTOK + pos] = tok;
    }
}

// ---------------- fp32 -> bf16 convert (Wdown) ----------------
__global__ void k_conv(const float* __restrict__ src, uint16_t* __restrict__ dst, int n4) {
    int stride = gridDim.x * blockDim.x;
    for (int i = blockIdx.x * blockDim.x + threadIdx.x; i < n4; i += stride) {
        float4 v = *(const float4*)(src + (size_t)i * 4);
        ushort4 h;
        h.x = f2bf(v.x); h.y = f2bf(v.y); h.z = f2bf(v.z); h.w = f2bf(v.w);
        *(ushort4*)(dst + (size_t)i * 4) = h;
    }
}

// ---------------- grouped NT GEMM: 256x256 tile, BK=32, 4-slot ring ----------------
// 512 threads = 8 waves (2M x 4N); per-wave C = 128x64 (acc[8][4] f32x4).
// LDS slot (32KB) chunk-major: A: addr = kchunk*4096 + row*16; B at +16384.
//   -> ds_read_b128 dense (conflict-free), global_load_lds linear dest with
//      one fixed gather row per thread (rule #21 satisfied trivially).
// Ring of 4 slots, stage lead 2 tiles, boundary wait vmcnt(4) (counted, not 0).
#define SLOTB 32768

template <int K, bool UP>
__global__ void __launch_bounds__(512, 1)
k_ffn3(const uint16_t* __restrict__ A, const uint16_t* __restrict__ Bw,
       const int* __restrict__ counts, const int* __restrict__ perm,
       uint16_t* __restrict__ hid_out, float* __restrict__ out) {
    constexpr int NOUT = UP ? DFF : DMODEL;
    constexpr int NT = K / 32;
    extern __shared__ char smem[];

    const int e = blockIdx.z;
    const int cnt = counts[e];
    const int bn0 = blockIdx.x * 256;
    const int tid = threadIdx.x;
    const int lane = tid & 63, wid = tid >> 6;
    const int wr = wid >> 2, wc = wid & 3;
    const int* permE = perm + e * NTOK;

    const int rowL = tid & 255;    // staging row (both A and B)
    const int hi   = tid >> 8;     // chunk-half select

    // B staging source (constant across y-loop); loads at +t*32 and +t*32+16
    const uint16_t* bPtr = Bw + ((size_t)e * NOUT + bn0 + rowL) * K + hi * 8;

    // staging LDS dest bases (wave-uniform; HW adds lane*16)
    char* stA = smem + wid * 1024;
    char* stB = smem + 16384 + wid * 1024;

    // fragment read bases (chunk-major)
    const char* aBase = smem + (lane >> 4) * 4096 + wr * 2048 + (lane & 15) * 16;
    const char* bBase = smem + 16384 + (lane >> 4) * 4096 + wc * 1024 + (lane & 15) * 16;

    for (int yb = blockIdx.y; yb * 256 < cnt; yb += GY) {
        const int base = yb * 256;
        int rA = base + rowL;
        int tokA = permE[(rA < cnt) ? rA : base];
        const uint16_t* aPtr = A + (size_t)tokA * K + hi * 8;

        f32x4 acc[8][4];
        #pragma unroll
        for (int m = 0; m < 8; ++m)
            #pragma unroll
            for (int n = 0; n < 4; ++n) acc[m][n] = (f32x4){0.f, 0.f, 0.f, 0.f};

        // prologue: stage tiles 0,1
        #pragma unroll
        for (int tt = 0; tt < 2; ++tt) {
            STG(aPtr + tt * 32,      stA + tt * SLOTB);
            STG(aPtr + tt * 32 + 16, stA + tt * SLOTB + 8192);
            STG(bPtr + tt * 32,      stB + tt * SLOTB);
            STG(bPtr + tt * 32 + 16, stB + tt * SLOTB + 8192);
        }
        asm volatile("s_waitcnt vmcnt(4)" ::: "memory");
        __builtin_amdgcn_sched_barrier(0);
        __builtin_amdgcn_s_barrier();

        bf16x8 aF[4], bF[4];
        #pragma unroll 1
        for (int t = 0; t < NT; ++t) {
            const int sp = (t & 3) * SLOTB;
            const bool pre = (t + 2) < NT;
            const int ss = ((t + 2) & 3) * SLOTB;
            // ---- phase 0: quadrant m0-3 x n0-3 ----
            #pragma unroll
            for (int m = 0; m < 4; ++m) aF[m] = *(const bf16x8*)(aBase + sp + m * 256);
            #pragma unroll
            for (int n = 0; n < 4; ++n) bF[n] = *(const bf16x8*)(bBase + sp + n * 256);
            if (pre) {
                STG(aPtr + (t + 2) * 32,      stA + ss);
                STG(aPtr + (t + 2) * 32 + 16, stA + ss + 8192);
            }
            __builtin_amdgcn_s_barrier();
            asm volatile("s_waitcnt lgkmcnt(0)" ::: "memory");
            __builtin_amdgcn_sched_barrier(0);
            __builtin_amdgcn_s_setprio(1);
            #pragma unroll
            for (int m = 0; m < 4; ++m)
                #pragma unroll
                for (int n = 0; n < 4; ++n)
                    acc[m][n] = __builtin_amdgcn_mfma_f32_16x16x32_bf16(aF[m], bF[n], acc[m][n], 0, 0, 0);
            __builtin_amdgcn_s_setprio(0);
            // ---- phase 1: quadrant m4-7 x n0-3 (B frags reused) ----
            #pragma unroll
            for (int m = 0; m < 4; ++m) aF[m] = *(const bf16x8*)(aBase + sp + 1024 + m * 256);
            if (pre) {
                STG(bPtr + (t + 2) * 32,      stB + ss);
                STG(bPtr + (t + 2) * 32 + 16, stB + ss + 8192);
                asm volatile("s_waitcnt vmcnt(4)" ::: "memory");
            } else {
                asm volatile("s_waitcnt vmcnt(0)" ::: "memory");
            }
            __builtin_amdgcn_sched_barrier(0);
            __builtin_amdgcn_s_barrier();
            asm volatile("s_waitcnt lgkmcnt(0)" ::: "memory");
            __builtin_amdgcn_sched_barrier(0);
            __builtin_amdgcn_s_setprio(1);
            #pragma unroll
            for (int m = 0; m < 4; ++m)
                #pragma unroll
                for (int n = 0; n < 4; ++n)
                    acc[4 + m][n] = __builtin_amdgcn_mfma_f32_16x16x32_bf16(aF[m], bF[n], acc[4 + m][n], 0, 0, 0);
            __builtin_amdgcn_s_setprio(0);
        }

        // epilogue: C[r][c], r = wr*128 + m*16 + (lane>>4)*4 + i, c = wc*64 + n*16 + (lane&15)
        #pragma unroll
        for (int m = 0; m < 8; ++m) {
            #pragma unroll
            for (int i = 0; i < 4; ++i) {
                int r  = wr * 128 + m * 16 + (lane >> 4) * 4 + i;
                int rr = base + r;
                if (rr < cnt) {
                    int tok = permE[rr];
                    if constexpr (UP) {
                        uint16_t* hr = hid_out + (size_t)tok * DFF + bn0 + wc * 64;
                        #pragma unroll
                        for (int n = 0; n < 4; ++n) {
                            float v = acc[m][n][i];
                            v = v > 0.f ? v : 0.f;
                            hr[n * 16 + (lane & 15)] = f2bf(v);
                        }
                    } else {
                        float* orow = out + (size_t)tok * DMODEL + bn0 + wc * 64;
                        #pragma unroll
                        for (int n = 0; n < 4; ++n)
                            orow[n * 16 + (lane & 15)] = acc[m][n][i];
                    }
                }
            }
        }
        __builtin_amdgcn_s_barrier();   // separate epilogue from next-iter staging
    }
}

extern "C" void kernel_launch(void* const* d_in, const int* in_sizes, int n_in,
                              void* d_out, int out_size, void* d_ws, size_t ws_size,
                              hipStream_t stream) {
    const float* x     = (const float*)d_in[0];
    const float* Wup   = (const float*)d_in[1];
    const float* Wdown = (const float*)d_in[2];
    float* out  = (float*)d_out;
    float* gate = out + (size_t)NTOK * DMODEL;

    char* ws = (char*)d_ws;
    size_t off = 0;
    auto alloc = [&](size_t bytes) -> void* {
        void* p = ws + off;
        off += (bytes + 255) & ~(size_t)255;
        return p;
    };
    int*      counts  = (int*)alloc(NTILES * sizeof(int));
    float*    sig     = (float*)alloc((size_t)NTILES * DMODEL * sizeof(float));
    double*   partial = (double*)alloc((size_t)NTILES * DMODEL * 64 * sizeof(double));
    int*      perm    = (int*)alloc((size_t)NTILES * NTOK * sizeof(int));
    uint16_t* xb      = (uint16_t*)alloc((size_t)NTOK * DMODEL * 2);
    uint16_t* wupb    = (uint16_t*)alloc((size_t)NTILES * DFF * DMODEL * 2);
    uint16_t* wdownb  = (uint16_t*)alloc((size_t)NTILES * DMODEL * DFF * 2);
    uint16_t* hidden  = (uint16_t*)alloc((size_t)NTOK * DFF * 2);
    if (off > ws_size) return;

    hipFuncSetAttribute((const void*)&k_ffn3<DMODEL, true>,
                        hipFuncAttributeMaxDynamicSharedMemorySize, 4 * SLOTB);
    hipFuncSetAttribute((const void*)&k_ffn3<DFF, false>,
                        hipFuncAttributeMaxDynamicSharedMemorySize, 4 * SLOTB);

    hipLaunchKernelGGL(k_convup, dim3(64, 4), dim3(256), 0, stream, Wup, wupb, partial);
    hipLaunchKernelGGL(k_sig_final, dim3(16), dim3(256), 0, stream, partial, sig, counts);
    hipLaunchKernelGGL(k_route, dim3(NTOK / 4), dim3(256), 0, stream,
                       x, sig, xb, gate, counts, perm);
    hipLaunchKernelGGL(k_conv, dim3(2048), dim3(256), 0, stream,
                       Wdown, wdownb, NTILES * DMODEL * DFF / 4);
    hipLaunchKernelGGL((k_ffn3<DMODEL, true>), dim3(DFF / 256, GY, NTILES),
                       dim3(512), 4 * SLOTB, stream, xb, wupb, counts, perm, hidden, nullptr);
    hipLaunchKernelGGL((k_ffn3<DFF, false>), dim3(DMODEL / 256, GY, NTILES),
                       dim3(512), 4 * SLOTB, stream, hidden, wdownb, counts, perm, nullptr, out);
}

// Round 4
// 705.562 us; speedup vs baseline: 1.1073x; 1.1073x over previous
//
#include <hip/hip_runtime.h>
#include <hip/hip_bf16.h>
#include <stdint.h>

#define NTILES 4
#define DMODEL 1024
#define DFF    4096
#define NTOK   16384
#define GY     20

typedef __bf16 bf16x8 __attribute__((ext_vector_type(8)));
typedef float  f32x4  __attribute__((ext_vector_type(4)));

__device__ __forceinline__ uint16_t f2bf(float f) {
    union { float f; uint32_t u; } v; v.f = f;
    uint32_t u = v.u;
    uint32_t r = (u + 0x7fffu + ((u >> 16) & 1u)) >> 16;
    return (uint16_t)r;
}

#define STG(gptr, ldsptr) __builtin_amdgcn_global_load_lds( \
    (__attribute__((address_space(1))) void*)(gptr), \
    (__attribute__((address_space(3))) void*)(ldsptr), 16, 0, 0)

// ---------------- fused Wup fp32->bf16 convert + signature partial sums ----------------
// grid (256 fb, 4 e), 256 threads; block handles 16 f-rows x 1024 cols.
__global__ void k_convup(const float* __restrict__ Wup, uint16_t* __restrict__ wupb,
                         double* __restrict__ partial) {
    int e = blockIdx.y, fb = blockIdx.x, tid = threadIdx.x;
    const float* src = Wup + (size_t)e * DFF * DMODEL + (size_t)fb * 16 * DMODEL + tid * 4;
    uint16_t*    dst = wupb + (size_t)e * DFF * DMODEL + (size_t)fb * 16 * DMODEL + tid * 4;
    double s0 = 0, s1 = 0, s2 = 0, s3 = 0;
    #pragma unroll 4
    for (int i = 0; i < 16; ++i) {
        float4 v = *(const float4*)(src + (size_t)i * DMODEL);
        ushort4 h;
        h.x = f2bf(v.x); h.y = f2bf(v.y); h.z = f2bf(v.z); h.w = f2bf(v.w);
        *(ushort4*)(dst + (size_t)i * DMODEL) = h;
        s0 += v.x; s1 += v.y; s2 += v.z; s3 += v.w;
    }
    int c = tid * 4;
    double* p = partial + ((size_t)e * DMODEL + c) * 256 + fb;
    p[0 * 256] = s0; p[1 * 256] = s1; p[2 * 256] = s2; p[3 * 256] = s3;
}

// signature finalize + zero expert counts (runs before k_route)
__global__ void k_sig_final(const double* __restrict__ partial, float* __restrict__ sig,
                            int* __restrict__ counts) {
    int idx = blockIdx.x * 256 + threadIdx.x;   // 0..4095
    if (blockIdx.x == 0 && threadIdx.x < NTILES) counts[threadIdx.x] = 0;
    double s = 0.0;
    for (int fb = 0; fb < 256; ++fb) s += partial[(size_t)idx * 256 + fb];
    sig[idx] = (s > 0.0) ? 1.0f : ((s < 0.0) ? -1.0f : 0.0f);
}

// ---------------- routing: scores, argmax, gate, xb (bf16 copy), buckets ----------------
__global__ void __launch_bounds__(256) k_route(const float* __restrict__ x,
                                               const float* __restrict__ sig,
                                               uint16_t* __restrict__ xb,
                                               float* __restrict__ gate_out,
                                               int* __restrict__ counts,
                                               int* __restrict__ perm) {
    __shared__ float sl[NTILES * DMODEL];
    for (int i = threadIdx.x; i < NTILES * DMODEL; i += 256) sl[i] = sig[i];
    __syncthreads();
    int wave = threadIdx.x >> 6, lane = threadIdx.x & 63;
    int tok = blockIdx.x * 4 + wave;
    const float* xr = x + (size_t)tok * DMODEL;
    float sc[NTILES] = {0.f, 0.f, 0.f, 0.f};
    for (int q = 0; q < 4; ++q) {
        int c = q * 256 + lane * 4;
        float4 xv = *(const float4*)(xr + c);
        #pragma unroll
        for (int t = 0; t < NTILES; ++t) {
            const float* st = sl + t * DMODEL + c;
            sc[t] += xv.x * st[0] + xv.y * st[1] + xv.z * st[2] + xv.w * st[3];
        }
        ushort4 h;
        h.x = f2bf(xv.x); h.y = f2bf(xv.y); h.z = f2bf(xv.z); h.w = f2bf(xv.w);
        *(ushort4*)(xb + (size_t)tok * DMODEL + c) = h;
    }
    #pragma unroll
    for (int t = 0; t < NTILES; ++t)
        for (int off = 32; off; off >>= 1) sc[t] += __shfl_xor(sc[t], off);
    int w = 0; float best = sc[0];
    if (sc[1] > best) { best = sc[1]; w = 1; }
    if (sc[2] > best) { best = sc[2]; w = 2; }
    if (sc[3] > best) { best = sc[3]; w = 3; }
    if (lane < NTILES) gate_out[(size_t)tok * NTILES + lane] = (lane == w) ? 1.0f : 0.0f;
    if (lane == 0) {
        int pos = atomicAdd(&counts[w], 1);
        perm[w * NTOK + pos] = tok;
    }
}

// ---------------- fp32 -> bf16 convert (Wdown) ----------------
__global__ void k_conv(const float* __restrict__ src, uint16_t* __restrict__ dst, int n4) {
    int stride = gridDim.x * blockDim.x;
    for (int i = blockIdx.x * blockDim.x + threadIdx.x; i < n4; i += stride) {
        float4 v = *(const float4*)(src + (size_t)i * 4);
        ushort4 h;
        h.x = f2bf(v.x); h.y = f2bf(v.y); h.z = f2bf(v.z); h.w = f2bf(v.w);
        *(ushort4*)(dst + (size_t)i * 4) = h;
    }
}

// ---------------- grouped NT GEMM: 256x256 tile, BK=64, 2-slot dbuf ----------------
// 512 threads = 8 waves (2M x 4N); per-wave C = 128x64 (acc[8][4]).
// LDS slot (64KB): A[256][64] linear rows (128B) at 0, B[256][64] at +32768.
//   Swizzle: phys_byte_in_row = logical ^ ((row&7)<<4)  (R2-proven, 0 conflicts).
//   Staging: coalesced — 8 lanes cover one row's 128B; src granule (i&7)^(row&7).
// Stage tile t+1 (8 loads/thread) at phase 0 of tile t into the other slot;
// boundary vmcnt(0) after ~3 phases of MFMA slack (pre-satisfied).
#define SLOT 65536

template <int K, bool UP>
__global__ void __launch_bounds__(512, 1)
k_ffn4(const uint16_t* __restrict__ A, const uint16_t* __restrict__ Bw,
       const int* __restrict__ counts, const int* __restrict__ perm,
       uint16_t* __restrict__ hid_out, float* __restrict__ out) {
    constexpr int NOUT = UP ? DFF : DMODEL;
    constexpr int NT = K / 64;
    extern __shared__ char smem[];

    const int e = blockIdx.z;
    const int cnt = counts[e];
    const int bn0 = blockIdx.x * 256;
    const int tid = threadIdx.x;
    const int lane = tid & 63, wid = tid >> 6;
    const int wr = wid >> 2, wc = wid & 3;
    const int* permE = perm + e * NTOK;

    // ---- staging geometry: instr j (0..3) covers row j*64 + srow, granule sgr
    const int srow = tid >> 3;                  // 0..63
    const int sgr  = (tid & 7) ^ (srow & 7);    // inverse-swizzled source granule

    const uint16_t* bP[4];
    #pragma unroll
    for (int j = 0; j < 4; ++j)
        bP[j] = Bw + ((size_t)e * NOUT + bn0 + j * 64 + srow) * K + sgr * 8;

    // wave-uniform LDS staging dest bases (HW adds lane*16)
    char* stA = smem + wid * 1024;              // + j*8192 (+ slot)
    char* stB = smem + 32768 + wid * 1024;

    // ---- fragment read bases (swizzled)
    const int inrow0 = (((lane >> 4) ^ (lane & 7)) << 4);
    const char* aRd[2], *bRd[2];
    aRd[0] = smem + (wr * 128 + (lane & 15)) * 128 + inrow0;
    aRd[1] = smem + (wr * 128 + (lane & 15)) * 128 + (inrow0 ^ 64);
    bRd[0] = smem + 32768 + (wc * 64 + (lane & 15)) * 128 + inrow0;
    bRd[1] = smem + 32768 + (wc * 64 + (lane & 15)) * 128 + (inrow0 ^ 64);

    for (int yb = blockIdx.y; yb * 256 < cnt; yb += GY) {
        const int base = yb * 256;

        // A gather pointers (4 rows per thread)
        const uint16_t* aP[4];
        #pragma unroll
        for (int j = 0; j < 4; ++j) {
            int rr = base + j * 64 + srow;
            int tok = permE[(rr < cnt) ? rr : base];
            aP[j] = A + (size_t)tok * K + sgr * 8;
        }

        f32x4 acc[8][4];
        #pragma unroll
        for (int m = 0; m < 8; ++m)
            #pragma unroll
            for (int n = 0; n < 4; ++n) acc[m][n] = (f32x4){0.f, 0.f, 0.f, 0.f};

        // prologue: stage tile 0 -> slot 0
        #pragma unroll
        for (int j = 0; j < 4; ++j) {
            STG(aP[j], stA + j * 8192);
            STG(bP[j], stB + j * 8192);
        }
        asm volatile("s_waitcnt vmcnt(0)" ::: "memory");
        __builtin_amdgcn_sched_barrier(0);
        __builtin_amdgcn_s_barrier();

        #pragma unroll 1
        for (int t = 0; t < NT; ++t) {
            const int sp = (t & 1) * SLOT;
            const int so = ((t & 1) ^ 1) * SLOT;
            const bool pre = (t + 1) < NT;
            bf16x8 aF[4], bF[4];

            // ---- phase 0: ks=0, m0-3 (+ stage tile t+1) ----
            #pragma unroll
            for (int m = 0; m < 4; ++m) aF[m] = *(const bf16x8*)(aRd[0] + sp + m * 2048);
            #pragma unroll
            for (int n = 0; n < 4; ++n) bF[n] = *(const bf16x8*)(bRd[0] + sp + n * 2048);
            if (pre) {
                #pragma unroll
                for (int j = 0; j < 4; ++j) {
                    STG(aP[j] + (t + 1) * 64, stA + so + j * 8192);
                    STG(bP[j] + (t + 1) * 64, stB + so + j * 8192);
                }
            }
            __builtin_amdgcn_s_barrier();
            asm volatile("s_waitcnt lgkmcnt(0)" ::: "memory");
            __builtin_amdgcn_sched_barrier(0);
            __builtin_amdgcn_s_setprio(1);
            #pragma unroll
            for (int m = 0; m < 4; ++m)
                #pragma unroll
                for (int n = 0; n < 4; ++n)
                    acc[m][n] = __builtin_amdgcn_mfma_f32_16x16x32_bf16(aF[m], bF[n], acc[m][n], 0, 0, 0);
            __builtin_amdgcn_s_setprio(0);
            __builtin_amdgcn_s_barrier();

            // ---- phase 1: ks=0, m4-7 (bF reused) ----
            #pragma unroll
            for (int m = 0; m < 4; ++m) aF[m] = *(const bf16x8*)(aRd[0] + sp + (m + 4) * 2048);
            __builtin_amdgcn_s_barrier();
            asm volatile("s_waitcnt lgkmcnt(0)" ::: "memory");
            __builtin_amdgcn_sched_barrier(0);
            __builtin_amdgcn_s_setprio(1);
            #pragma unroll
            for (int m = 0; m < 4; ++m)
                #pragma unroll
                for (int n = 0; n < 4; ++n)
                    acc[4 + m][n] = __builtin_amdgcn_mfma_f32_16x16x32_bf16(aF[m], bF[n], acc[4 + m][n], 0, 0, 0);
            __builtin_amdgcn_s_setprio(0);
            __builtin_amdgcn_s_barrier();

            // ---- phase 2: ks=1, m0-3 ----
            #pragma unroll
            for (int m = 0; m < 4; ++m) aF[m] = *(const bf16x8*)(aRd[1] + sp + m * 2048);
            #pragma unroll
            for (int n = 0; n < 4; ++n) bF[n] = *(const bf16x8*)(bRd[1] + sp + n * 2048);
            __builtin_amdgcn_s_barrier();
            asm volatile("s_waitcnt lgkmcnt(0)" ::: "memory");
            __builtin_amdgcn_sched_barrier(0);
            __builtin_amdgcn_s_setprio(1);
            #pragma unroll
            for (int m = 0; m < 4; ++m)
                #pragma unroll
                for (int n = 0; n < 4; ++n)
                    acc[m][n] = __builtin_amdgcn_mfma_f32_16x16x32_bf16(aF[m], bF[n], acc[m][n], 0, 0, 0);
            __builtin_amdgcn_s_setprio(0);
            __builtin_amdgcn_s_barrier();

            // ---- phase 3: ks=1, m4-7 (bF reused) + boundary wait ----
            #pragma unroll
            for (int m = 0; m < 4; ++m) aF[m] = *(const bf16x8*)(aRd[1] + sp + (m + 4) * 2048);
            __builtin_amdgcn_s_barrier();
            asm volatile("s_waitcnt lgkmcnt(0)" ::: "memory");
            __builtin_amdgcn_sched_barrier(0);
            __builtin_amdgcn_s_setprio(1);
            #pragma unroll
            for (int m = 0; m < 4; ++m)
                #pragma unroll
                for (int n = 0; n < 4; ++n)
                    acc[4 + m][n] = __builtin_amdgcn_mfma_f32_16x16x32_bf16(aF[m], bF[n], acc[4 + m][n], 0, 0, 0);
            __builtin_amdgcn_s_setprio(0);
            if (pre) {
                asm volatile("s_waitcnt vmcnt(0)" ::: "memory");
                __builtin_amdgcn_sched_barrier(0);
            }
            __builtin_amdgcn_s_barrier();
        }

        // epilogue: r = wr*128 + m*16 + (lane>>4)*4 + i, c = wc*64 + n*16 + (lane&15)
        #pragma unroll
        for (int m = 0; m < 8; ++m) {
            #pragma unroll
            for (int i = 0; i < 4; ++i) {
                int r  = wr * 128 + m * 16 + (lane >> 4) * 4 + i;
                int rr = base + r;
                if (rr < cnt) {
                    int tok = permE[rr];
                    if constexpr (UP) {
                        uint16_t* hr = hid_out + (size_t)tok * DFF + bn0 + wc * 64;
                        #pragma unroll
                        for (int n = 0; n < 4; ++n) {
                            float v = acc[m][n][i];
                            v = v > 0.f ? v : 0.f;
                            hr[n * 16 + (lane & 15)] = f2bf(v);
                        }
                    } else {
                        float* orow = out + (size_t)tok * DMODEL + bn0 + wc * 64;
                        #pragma unroll
                        for (int n = 0; n < 4; ++n)
                            orow[n * 16 + (lane & 15)] = acc[m][n][i];
                    }
                }
            }
        }
        __builtin_amdgcn_s_barrier();   // separate epilogue from next y-iter staging
    }
}

extern "C" void kernel_launch(void* const* d_in, const int* in_sizes, int n_in,
                              void* d_out, int out_size, void* d_ws, size_t ws_size,
                              hipStream_t stream) {
    const float* x     = (const float*)d_in[0];
    const float* Wup   = (const float*)d_in[1];
    const float* Wdown = (const float*)d_in[2];
    float* out  = (float*)d_out;
    float* gate = out + (size_t)NTOK * DMODEL;

    char* ws = (char*)d_ws;
    size_t off = 0;
    auto alloc = [&](size_t bytes) -> void* {
        void* p = ws + off;
        off += (bytes + 255) & ~(size_t)255;
        return p;
    };
    int*      counts  = (int*)alloc(NTILES * sizeof(int));
    float*    sig     = (float*)alloc((size_t)NTILES * DMODEL * sizeof(float));
    double*   partial = (double*)alloc((size_t)NTILES * DMODEL * 256 * sizeof(double));
    int*      perm    = (int*)alloc((size_t)NTILES * NTOK * sizeof(int));
    uint16_t* xb      = (uint16_t*)alloc((size_t)NTOK * DMODEL * 2);
    uint16_t* wupb    = (uint16_t*)alloc((size_t)NTILES * DFF * DMODEL * 2);
    uint16_t* wdownb  = (uint16_t*)alloc((size_t)NTILES * DMODEL * DFF * 2);
    uint16_t* hidden  = (uint16_t*)alloc((size_t)NTOK * DFF * 2);
    if (off > ws_size) return;

    hipFuncSetAttribute((const void*)&k_ffn4<DMODEL, true>,
                        hipFuncAttributeMaxDynamicSharedMemorySize, 2 * SLOT);
    hipFuncSetAttribute((const void*)&k_ffn4<DFF, false>,
                        hipFuncAttributeMaxDynamicSharedMemorySize, 2 * SLOT);

    hipLaunchKernelGGL(k_convup, dim3(256, 4), dim3(256), 0, stream, Wup, wupb, partial);
    hipLaunchKernelGGL(k_sig_final, dim3(16), dim3(256), 0, stream, partial, sig, counts);
    hipLaunchKernelGGL(k_route, dim3(NTOK / 4), dim3(256), 0, stream,
                       x, sig, xb, gate, counts, perm);
    hipLaunchKernelGGL(k_conv, dim3(2048), dim3(256), 0, stream,
                       Wdown, wdownb, NTILES * DMODEL * DFF / 4);
    hipLaunchKernelGGL((k_ffn4<DMODEL, true>), dim3(DFF / 256, GY, NTILES),
                       dim3(512), 2 * SLOT, stream, xb, wupb, counts, perm, hidden, nullptr);
    hipLaunchKernelGGL((k_ffn4<DFF, false>), dim3(DMODEL / 256, GY, NTILES),
                       dim3(512), 2 * SLOT, stream, hidden, wdownb, counts, perm, nullptr, out);
}

// Round 5
// 678.900 us; speedup vs baseline: 1.1508x; 1.0393x over previous
//
#include <hip/hip_runtime.h>
#include <hip/hip_bf16.h>
#include <stdint.h>

#define NTILES 4
#define DMODEL 1024
#define DFF    4096
#define NTOK   16384

typedef __bf16 bf16x8 __attribute__((ext_vector_type(8)));
typedef float  f32x4  __attribute__((ext_vector_type(4)));

__device__ __forceinline__ uint16_t f2bf(float f) {
    union { float f; uint32_t u; } v; v.f = f;
    uint32_t u = v.u;
    uint32_t r = (u + 0x7fffu + ((u >> 16) & 1u)) >> 16;
    return (uint16_t)r;
}

#define STG(gptr, ldsptr) __builtin_amdgcn_global_load_lds( \
    (__attribute__((address_space(1))) void*)(gptr), \
    (__attribute__((address_space(3))) void*)(ldsptr), 16, 0, 0)

// ---------------- fused Wup fp32->bf16 convert + signature partial sums ----------------
__global__ void k_convup(const float* __restrict__ Wup, uint16_t* __restrict__ wupb,
                         double* __restrict__ partial) {
    int e = blockIdx.y, fb = blockIdx.x, tid = threadIdx.x;
    const float* src = Wup + (size_t)e * DFF * DMODEL + (size_t)fb * 16 * DMODEL + tid * 4;
    uint16_t*    dst = wupb + (size_t)e * DFF * DMODEL + (size_t)fb * 16 * DMODEL + tid * 4;
    double s0 = 0, s1 = 0, s2 = 0, s3 = 0;
    #pragma unroll 4
    for (int i = 0; i < 16; ++i) {
        float4 v = *(const float4*)(src + (size_t)i * DMODEL);
        ushort4 h;
        h.x = f2bf(v.x); h.y = f2bf(v.y); h.z = f2bf(v.z); h.w = f2bf(v.w);
        *(ushort4*)(dst + (size_t)i * DMODEL) = h;
        s0 += v.x; s1 += v.y; s2 += v.z; s3 += v.w;
    }
    int c = tid * 4;
    double* p = partial + ((size_t)e * DMODEL + c) * 256 + fb;
    p[0 * 256] = s0; p[1 * 256] = s1; p[2 * 256] = s2; p[3 * 256] = s3;
}

// signature finalize (parallel) + zero expert counts
__global__ void k_sig_final(const double* __restrict__ partial, float* __restrict__ sig,
                            int* __restrict__ counts) {
    int b = blockIdx.x;                 // 0..511
    int sub = threadIdx.x >> 5;         // 0..7
    int l32 = threadIdx.x & 31;
    int idx = b * 8 + sub;              // 0..4095
    const double* p = partial + (size_t)idx * 256 + l32;
    double s = 0.0;
    #pragma unroll
    for (int i = 0; i < 8; ++i) s += p[i * 32];
    #pragma unroll
    for (int off = 16; off; off >>= 1) s += __shfl_xor(s, off);
    if (l32 == 0) sig[idx] = (s > 0.0) ? 1.0f : ((s < 0.0) ? -1.0f : 0.0f);
    if (b == 0 && threadIdx.x < NTILES) counts[threadIdx.x] = 0;
}

// ---------------- routing: scores, argmax, gate, xb (bf16 copy), buckets ----------------
__global__ void __launch_bounds__(256) k_route(const float* __restrict__ x,
                                               const float* __restrict__ sig,
                                               uint16_t* __restrict__ xb,
                                               float* __restrict__ gate_out,
                                               int* __restrict__ counts,
                                               int* __restrict__ perm) {
    __shared__ float sl[NTILES * DMODEL];
    for (int i = threadIdx.x; i < NTILES * DMODEL; i += 256) sl[i] = sig[i];
    __syncthreads();
    int wave = threadIdx.x >> 6, lane = threadIdx.x & 63;
    int tok = blockIdx.x * 4 + wave;
    const float* xr = x + (size_t)tok * DMODEL;
    float sc[NTILES] = {0.f, 0.f, 0.f, 0.f};
    for (int q = 0; q < 4; ++q) {
        int c = q * 256 + lane * 4;
        float4 xv = *(const float4*)(xr + c);
        #pragma unroll
        for (int t = 0; t < NTILES; ++t) {
            const float* st = sl + t * DMODEL + c;
            sc[t] += xv.x * st[0] + xv.y * st[1] + xv.z * st[2] + xv.w * st[3];
        }
        ushort4 h;
        h.x = f2bf(xv.x); h.y = f2bf(xv.y); h.z = f2bf(xv.z); h.w = f2bf(xv.w);
        *(ushort4*)(xb + (size_t)tok * DMODEL + c) = h;
    }
    #pragma unroll
    for (int t = 0; t < NTILES; ++t)
        for (int off = 32; off; off >>= 1) sc[t] += __shfl_xor(sc[t], off);
    int w = 0; float best = sc[0];
    if (sc[1] > best) { best = sc[1]; w = 1; }
    if (sc[2] > best) { best = sc[2]; w = 2; }
    if (sc[3] > best) { best = sc[3]; w = 3; }
    if (lane < NTILES) gate_out[(size_t)tok * NTILES + lane] = (lane == w) ? 1.0f : 0.0f;
    if (lane == 0) {
        int pos = atomicAdd(&counts[w], 1);
        perm[w * NTOK + pos] = tok;
    }
}

// ---------------- fp32 -> bf16 convert (Wdown) ----------------
__global__ void k_conv(const float* __restrict__ src, uint16_t* __restrict__ dst, int n4) {
    int stride = gridDim.x * blockDim.x;
    for (int i = blockIdx.x * blockDim.x + threadIdx.x; i < n4; i += stride) {
        float4 v = *(const float4*)(src + (size_t)i * 4);
        ushort4 h;
        h.x = f2bf(v.x); h.y = f2bf(v.y); h.z = f2bf(v.z); h.w = f2bf(v.w);
        *(ushort4*)(dst + (size_t)i * 4) = h;
    }
}

// ---------------- grouped NT GEMM: 256x256 tile, K-tile=32, 4-slot ring ----------------
// 512 threads = 8 waves (2M x 4N); per-wave C = 128x64 (acc[8][4]).
// Slot (32KB): A[256 rows x 64B] at 0, B at +16384.  Pair-interleaved lines:
//   line q (128B) holds rows {2q,2q+1}; granule slot s' holds logical l = s'^(q&7),
//   l = 4*rowparity + kgranule.  -> frag ds_read_b128 is 2-way bank-aliased (free),
//   staging is lane-linear (global_load_lds) with per-lane inverse-swizzled source.
// 3-tile lookahead: during tile t issue tile t+3 (2 loads/phase); boundary wait
// vmcnt(8) (tail 4/0) — counted, never drains mid-loop.
#define SLOTB 32768

template <int K, bool UP>
__global__ void __launch_bounds__(512, 1)
k_ffn5(const uint16_t* __restrict__ A, const uint16_t* __restrict__ Bw,
       const int* __restrict__ counts, const int* __restrict__ perm,
       uint16_t* __restrict__ hid_out, float* __restrict__ out) {
    constexpr int NOUT = UP ? DFF : DMODEL;
    constexpr int NT = K / 32;
    extern __shared__ char smem[];

    const int e = blockIdx.z;
    const int cnt = counts[e];
    int cofs = 0;
    #pragma unroll
    for (int i = 0; i < NTILES; ++i) if (i < e) cofs += counts[i];
    const int bn0 = blockIdx.x * 256;
    const int tid = threadIdx.x;
    const int lane = tid & 63, wid = tid >> 6;
    const int wr = wid >> 2, wc = wid & 3;
    const int* permE = perm + e * NTOK;

    // ---- staging thread decode: line qs (0..63 within instr), slot s'=tid&7
    const int qs = tid >> 3;
    const int ls = (tid & 7) ^ (qs & 7);
    const int us = ls >> 2, gs = ls & 3;    // row parity, k-granule

    // B staging sources: instr j covers tile rows j*128 + 2*qs + us
    const uint16_t* bP[2];
    #pragma unroll
    for (int j = 0; j < 2; ++j)
        bP[j] = Bw + ((size_t)e * NOUT + bn0 + j * 128 + 2 * qs + us) * K + gs * 8;

    // wave-uniform LDS staging dest bases (HW adds lane*16)
    char* stA = smem + wid * 1024;
    char* stB = smem + 16384 + wid * 1024;

    // ---- fragment read offsets (within slot); frag stride 1024B
    const int r0a = wr * 128 + (lane & 15);
    const int qa  = r0a >> 1;
    const int sa  = (((r0a & 1) << 2) | (lane >> 4)) ^ (qa & 7);
    const int Aoff = qa * 128 + sa * 16;
    const int r0b = wc * 64 + (lane & 15);
    const int qb  = r0b >> 1;
    const int sb  = (((r0b & 1) << 2) | (lane >> 4)) ^ (qb & 7);
    const int Boff = 16384 + qb * 128 + sb * 16;

    for (int yb = blockIdx.y; yb * 256 < cnt; yb += gridDim.y) {
        const int base = yb * 256;

        // A staging sources
        const uint16_t* aP[2];
        #pragma unroll
        for (int j = 0; j < 2; ++j) {
            int rowj = j * 128 + 2 * qs + us;
            if constexpr (UP) {
                int rr = base + rowj;
                int tok = permE[(rr < cnt) ? rr : base];
                aP[j] = A + (size_t)tok * K + gs * 8;
            } else {
                aP[j] = A + (size_t)(cofs + base + rowj) * K + gs * 8;
            }
        }

        f32x4 acc[8][4];
        #pragma unroll
        for (int m = 0; m < 8; ++m)
            #pragma unroll
            for (int n = 0; n < 4; ++n) acc[m][n] = (f32x4){0.f, 0.f, 0.f, 0.f};

        // prologue: stage tiles 0,1,2 -> slots 0,1,2 (12 loads)
        #pragma unroll
        for (int tt = 0; tt < 3; ++tt) {
            STG(aP[0] + tt * 32, stA + tt * SLOTB);
            STG(aP[1] + tt * 32, stA + tt * SLOTB + 8192);
            STG(bP[0] + tt * 32, stB + tt * SLOTB);
            STG(bP[1] + tt * 32, stB + tt * SLOTB + 8192);
        }
        asm volatile("s_waitcnt vmcnt(8)" ::: "memory");
        __builtin_amdgcn_sched_barrier(0);
        __builtin_amdgcn_s_barrier();

        #pragma unroll 1
        for (int t = 0; t < NT; ++t) {
            const char* sp = smem + (t & 3) * SLOTB;
            const int ss = ((t + 3) & 3) * SLOTB;
            const bool pre = (t + 3) < NT;
            bf16x8 aF[4], bF[4];

            // ---- phase 0: m0-3 x n0-3 ----
            #pragma unroll
            for (int m = 0; m < 4; ++m) aF[m] = *(const bf16x8*)(sp + Aoff + m * 1024);
            #pragma unroll
            for (int n = 0; n < 4; ++n) bF[n] = *(const bf16x8*)(sp + Boff + n * 1024);
            if (pre) {
                STG(aP[0] + (t + 3) * 32, stA + ss);
                STG(aP[1] + (t + 3) * 32, stA + ss + 8192);
            }
            __builtin_amdgcn_s_barrier();
            asm volatile("s_waitcnt lgkmcnt(0)" ::: "memory");
            __builtin_amdgcn_sched_barrier(0);
            __builtin_amdgcn_s_setprio(1);
            #pragma unroll
            for (int m = 0; m < 4; ++m)
                #pragma unroll
                for (int n = 0; n < 4; ++n)
                    acc[m][n] = __builtin_amdgcn_mfma_f32_16x16x32_bf16(aF[m], bF[n], acc[m][n], 0, 0, 0);
            __builtin_amdgcn_s_setprio(0);
            __builtin_amdgcn_s_barrier();

            // ---- phase 1: m4-7 x n0-3 (bF reused) ----
            #pragma unroll
            for (int m = 0; m < 4; ++m) aF[m] = *(const bf16x8*)(sp + Aoff + (m + 4) * 1024);
            if (pre) {
                STG(bP[0] + (t + 3) * 32, stB + ss);
                STG(bP[1] + (t + 3) * 32, stB + ss + 8192);
            }
            __builtin_amdgcn_s_barrier();
            asm volatile("s_waitcnt lgkmcnt(0)" ::: "memory");
            __builtin_amdgcn_sched_barrier(0);
            __builtin_amdgcn_s_setprio(1);
            #pragma unroll
            for (int m = 0; m < 4; ++m)
                #pragma unroll
                for (int n = 0; n < 4; ++n)
                    acc[4 + m][n] = __builtin_amdgcn_mfma_f32_16x16x32_bf16(aF[m], bF[n], acc[4 + m][n], 0, 0, 0);
            __builtin_amdgcn_s_setprio(0);
            // boundary wait (counted; tail shrinks)
            if (t < NT - 3)       { asm volatile("s_waitcnt vmcnt(8)" ::: "memory"); }
            else if (t == NT - 3) { asm volatile("s_waitcnt vmcnt(4)" ::: "memory"); }
            else if (t == NT - 2) { asm volatile("s_waitcnt vmcnt(0)" ::: "memory"); }
            __builtin_amdgcn_sched_barrier(0);
            __builtin_amdgcn_s_barrier();
        }

        // epilogue: r = wr*128 + m*16 + (lane>>4)*4 + i, c = wc*64 + n*16 + (lane&15)
        #pragma unroll
        for (int m = 0; m < 8; ++m) {
            #pragma unroll
            for (int i = 0; i < 4; ++i) {
                int r  = wr * 128 + m * 16 + (lane >> 4) * 4 + i;
                int rr = base + r;
                if (rr < cnt) {
                    if constexpr (UP) {
                        uint16_t* hr = hid_out + (size_t)(cofs + rr) * DFF + bn0 + wc * 64;
                        #pragma unroll
                        for (int n = 0; n < 4; ++n) {
                            float v = acc[m][n][i];
                            v = v > 0.f ? v : 0.f;
                            hr[n * 16 + (lane & 15)] = f2bf(v);
                        }
                    } else {
                        float* orow = out + (size_t)permE[rr] * DMODEL + bn0 + wc * 64;
                        #pragma unroll
                        for (int n = 0; n < 4; ++n)
                            orow[n * 16 + (lane & 15)] = acc[m][n][i];
                    }
                }
            }
        }
    }
}

extern "C" void kernel_launch(void* const* d_in, const int* in_sizes, int n_in,
                              void* d_out, int out_size, void* d_ws, size_t ws_size,
                              hipStream_t stream) {
    const float* x     = (const float*)d_in[0];
    const float* Wup   = (const float*)d_in[1];
    const float* Wdown = (const float*)d_in[2];
    float* out  = (float*)d_out;
    float* gate = out + (size_t)NTOK * DMODEL;

    char* ws = (char*)d_ws;
    size_t off = 0;
    auto alloc = [&](size_t bytes) -> void* {
        void* p = ws + off;
        off += (bytes + 255) & ~(size_t)255;
        return p;
    };
    int*      counts  = (int*)alloc(NTILES * sizeof(int));
    float*    sig     = (float*)alloc((size_t)NTILES * DMODEL * sizeof(float));
    double*   partial = (double*)alloc((size_t)NTILES * DMODEL * 256 * sizeof(double));
    int*      perm    = (int*)alloc((size_t)NTILES * NTOK * sizeof(int));
    uint16_t* xb      = (uint16_t*)alloc((size_t)NTOK * DMODEL * 2);
    uint16_t* wupb    = (uint16_t*)alloc((size_t)NTILES * DFF * DMODEL * 2);
    uint16_t* wdownb  = (uint16_t*)alloc((size_t)NTILES * DMODEL * DFF * 2);
    uint16_t* hidden  = (uint16_t*)alloc(((size_t)NTOK + 256) * DFF * 2);
    if (off > ws_size) return;

    hipFuncSetAttribute((const void*)&k_ffn5<DMODEL, true>,
                        hipFuncAttributeMaxDynamicSharedMemorySize, 4 * SLOTB);
    hipFuncSetAttribute((const void*)&k_ffn5<DFF, false>,
                        hipFuncAttributeMaxDynamicSharedMemorySize, 4 * SLOTB);

    hipLaunchKernelGGL(k_convup, dim3(256, 4), dim3(256), 0, stream, Wup, wupb, partial);
    hipLaunchKernelGGL(k_sig_final, dim3(512), dim3(256), 0, stream, partial, sig, counts);
    hipLaunchKernelGGL(k_route, dim3(NTOK / 4), dim3(256), 0, stream,
                       x, sig, xb, gate, counts, perm);
    hipLaunchKernelGGL(k_conv, dim3(2048), dim3(256), 0, stream,
                       Wdown, wdownb, NTILES * DMODEL * DFF / 4);
    hipLaunchKernelGGL((k_ffn5<DMODEL, true>), dim3(DFF / 256, 4, NTILES),
                       dim3(512), 4 * SLOTB, stream, xb, wupb, counts, perm, hidden, nullptr);
    hipLaunchKernelGGL((k_ffn5<DFF, false>), dim3(DMODEL / 256, 16, NTILES),
                       dim3(512), 4 * SLOTB, stream, hidden, wdownb, counts, perm, nullptr, out);
}

// Round 6
// 659.130 us; speedup vs baseline: 1.1853x; 1.0300x over previous
//
#include <hip/hip_runtime.h>
#include <hip/hip_bf16.h>
#include <stdint.h>

#define NTILES 4
#define DMODEL 1024
#define DFF    4096
#define NTOK   16384
#define MAXJOBS 68

typedef __bf16 bf16x8 __attribute__((ext_vector_type(8)));
typedef float  f32x4  __attribute__((ext_vector_type(4)));

__device__ __forceinline__ uint16_t f2bf(float f) {
    union { float f; uint32_t u; } v; v.f = f;
    uint32_t u = v.u;
    uint32_t r = (u + 0x7fffu + ((u >> 16) & 1u)) >> 16;
    return (uint16_t)r;
}

#define STG(gptr, ldsptr) __builtin_amdgcn_global_load_lds( \
    (__attribute__((address_space(1))) void*)(gptr), \
    (__attribute__((address_space(3))) void*)(ldsptr), 16, 0, 0)

// ---------------- fused Wup fp32->bf16 convert + signature partial sums ----------------
__global__ void k_convup(const float* __restrict__ Wup, uint16_t* __restrict__ wupb,
                         double* __restrict__ partial) {
    int e = blockIdx.y, fb = blockIdx.x, tid = threadIdx.x;
    const float* src = Wup + (size_t)e * DFF * DMODEL + (size_t)fb * 16 * DMODEL + tid * 4;
    uint16_t*    dst = wupb + (size_t)e * DFF * DMODEL + (size_t)fb * 16 * DMODEL + tid * 4;
    double s0 = 0, s1 = 0, s2 = 0, s3 = 0;
    #pragma unroll 4
    for (int i = 0; i < 16; ++i) {
        float4 v = *(const float4*)(src + (size_t)i * DMODEL);
        ushort4 h;
        h.x = f2bf(v.x); h.y = f2bf(v.y); h.z = f2bf(v.z); h.w = f2bf(v.w);
        *(ushort4*)(dst + (size_t)i * DMODEL) = h;
        s0 += v.x; s1 += v.y; s2 += v.z; s3 += v.w;
    }
    int c = tid * 4;
    double* p = partial + ((size_t)e * DMODEL + c) * 256 + fb;
    p[0 * 256] = s0; p[1 * 256] = s1; p[2 * 256] = s2; p[3 * 256] = s3;
}

// signature finalize (parallel) + zero expert counts
__global__ void k_sig_final(const double* __restrict__ partial, float* __restrict__ sig,
                            int* __restrict__ counts) {
    int b = blockIdx.x;                 // 0..511
    int sub = threadIdx.x >> 5;         // 0..7
    int l32 = threadIdx.x & 31;
    int idx = b * 8 + sub;              // 0..4095
    const double* p = partial + (size_t)idx * 256 + l32;
    double s = 0.0;
    #pragma unroll
    for (int i = 0; i < 8; ++i) s += p[i * 32];
    #pragma unroll
    for (int off = 16; off; off >>= 1) s += __shfl_xor(s, off);
    if (l32 == 0) sig[idx] = (s > 0.0) ? 1.0f : ((s < 0.0) ? -1.0f : 0.0f);
    if (b == 0 && threadIdx.x < NTILES) counts[threadIdx.x] = 0;
}

// ---------------- routing: scores, argmax, gate, xb (bf16 copy), buckets ----------------
__global__ void __launch_bounds__(256) k_route(const float* __restrict__ x,
                                               const float* __restrict__ sig,
                                               uint16_t* __restrict__ xb,
                                               float* __restrict__ gate_out,
                                               int* __restrict__ counts,
                                               int* __restrict__ perm) {
    __shared__ float sl[NTILES * DMODEL];
    for (int i = threadIdx.x; i < NTILES * DMODEL; i += 256) sl[i] = sig[i];
    __syncthreads();
    int wave = threadIdx.x >> 6, lane = threadIdx.x & 63;
    int tok = blockIdx.x * 4 + wave;
    const float* xr = x + (size_t)tok * DMODEL;
    float sc[NTILES] = {0.f, 0.f, 0.f, 0.f};
    for (int q = 0; q < 4; ++q) {
        int c = q * 256 + lane * 4;
        float4 xv = *(const float4*)(xr + c);
        #pragma unroll
        for (int t = 0; t < NTILES; ++t) {
            const float* st = sl + t * DMODEL + c;
            sc[t] += xv.x * st[0] + xv.y * st[1] + xv.z * st[2] + xv.w * st[3];
        }
        ushort4 h;
        h.x = f2bf(xv.x); h.y = f2bf(xv.y); h.z = f2bf(xv.z); h.w = f2bf(xv.w);
        *(ushort4*)(xb + (size_t)tok * DMODEL + c) = h;
    }
    #pragma unroll
    for (int t = 0; t < NTILES; ++t)
        for (int off = 32; off; off >>= 1) sc[t] += __shfl_xor(sc[t], off);
    int w = 0; float best = sc[0];
    if (sc[1] > best) { best = sc[1]; w = 1; }
    if (sc[2] > best) { best = sc[2]; w = 2; }
    if (sc[3] > best) { best = sc[3]; w = 3; }
    if (lane < NTILES) gate_out[(size_t)tok * NTILES + lane] = (lane == w) ? 1.0f : 0.0f;
    if (lane == 0) {
        int pos = atomicAdd(&counts[w], 1);
        perm[w * NTOK + pos] = tok;
    }
}

// ---------------- fp32 -> bf16 convert (Wdown) ----------------
__global__ void k_conv(const float* __restrict__ src, uint16_t* __restrict__ dst, int n4) {
    int stride = gridDim.x * blockDim.x;
    for (int i = blockIdx.x * blockDim.x + threadIdx.x; i < n4; i += stride) {
        float4 v = *(const float4*)(src + (size_t)i * 4);
        ushort4 h;
        h.x = f2bf(v.x); h.y = f2bf(v.y); h.z = f2bf(v.z); h.w = f2bf(v.w);
        *(ushort4*)(dst + (size_t)i * 4) = h;
    }
}

// ---------------- grouped NT GEMM: 256x256 tile, K-tile=32, 4-slot ring ----------------
// Job-flattened grid: blockIdx.y = job (expert,y-tile) decoded from counts prefix;
// blockIdx.x = N-tile (FASTEST dim -> x-partners sharing one A-tile are
// dispatch-adjacent & co-resident -> A fetched once from HBM, rest LLC hits).
// One job per block (no y-loop) -> no temporal drift, no expert imbalance.
// Schedule (R5): 512 thr = 8 waves (2M x 4N), per-wave C 128x64 (acc[8][4]);
// slot 32KB pair-interleaved-swizzled; 3-tile lookahead, vmcnt(8) counted.
#define SLOTB 32768

template <int K, bool UP>
__global__ void __launch_bounds__(512, 1)
k_ffn6(const uint16_t* __restrict__ A, const uint16_t* __restrict__ Bw,
       const int* __restrict__ counts, const int* __restrict__ perm,
       uint16_t* __restrict__ hid_out, float* __restrict__ out) {
    constexpr int NOUT = UP ? DFF : DMODEL;
    constexpr int NT = K / 32;
    extern __shared__ char smem[];

    // ---- job decode ----
    const int c0 = counts[0], c1 = counts[1], c2 = counts[2], c3 = counts[3];
    const int n0 = (c0 + 255) >> 8, n1 = (c1 + 255) >> 8, n2 = (c2 + 255) >> 8,
              n3 = (c3 + 255) >> 8;
    const int j = blockIdx.y;
    int e, yt, cnt, cofs;
    if (j < n0)                     { e = 0; yt = j;                cnt = c0; cofs = 0; }
    else if (j < n0 + n1)           { e = 1; yt = j - n0;           cnt = c1; cofs = c0; }
    else if (j < n0 + n1 + n2)      { e = 2; yt = j - n0 - n1;      cnt = c2; cofs = c0 + c1; }
    else if (j < n0 + n1 + n2 + n3) { e = 3; yt = j - n0 - n1 - n2; cnt = c3; cofs = c0 + c1 + c2; }
    else return;
    const int base = yt * 256;

    const int bn0 = blockIdx.x * 256;
    const int tid = threadIdx.x;
    const int lane = tid & 63, wid = tid >> 6;
    const int wr = wid >> 2, wc = wid & 3;
    const int* permE = perm + e * NTOK;

    // ---- staging thread decode: line qs, slot s'=tid&7 (inverse-swizzled)
    const int qs = tid >> 3;
    const int ls = (tid & 7) ^ (qs & 7);
    const int us = ls >> 2, gs = ls & 3;    // row parity, k-granule

    const uint16_t* bP[2];
    #pragma unroll
    for (int jj = 0; jj < 2; ++jj)
        bP[jj] = Bw + ((size_t)e * NOUT + bn0 + jj * 128 + 2 * qs + us) * K + gs * 8;

    const uint16_t* aP[2];
    #pragma unroll
    for (int jj = 0; jj < 2; ++jj) {
        int rowj = jj * 128 + 2 * qs + us;
        if constexpr (UP) {
            int rr = base + rowj;
            int tok = permE[(rr < cnt) ? rr : base];
            aP[jj] = A + (size_t)tok * K + gs * 8;
        } else {
            aP[jj] = A + (size_t)(cofs + base + rowj) * K + gs * 8;
        }
    }

    // wave-uniform LDS staging dest bases (HW adds lane*16)
    char* stA = smem + wid * 1024;
    char* stB = smem + 16384 + wid * 1024;

    // ---- fragment read offsets (within slot); frag stride 1024B
    const int r0a = wr * 128 + (lane & 15);
    const int qa  = r0a >> 1;
    const int sa  = (((r0a & 1) << 2) | (lane >> 4)) ^ (qa & 7);
    const int Aoff = qa * 128 + sa * 16;
    const int r0b = wc * 64 + (lane & 15);
    const int qb  = r0b >> 1;
    const int sb  = (((r0b & 1) << 2) | (lane >> 4)) ^ (qb & 7);
    const int Boff = 16384 + qb * 128 + sb * 16;

    f32x4 acc[8][4];
    #pragma unroll
    for (int m = 0; m < 8; ++m)
        #pragma unroll
        for (int n = 0; n < 4; ++n) acc[m][n] = (f32x4){0.f, 0.f, 0.f, 0.f};

    // prologue: stage tiles 0,1,2 -> slots 0,1,2
    #pragma unroll
    for (int tt = 0; tt < 3; ++tt) {
        STG(aP[0] + tt * 32, stA + tt * SLOTB);
        STG(aP[1] + tt * 32, stA + tt * SLOTB + 8192);
        STG(bP[0] + tt * 32, stB + tt * SLOTB);
        STG(bP[1] + tt * 32, stB + tt * SLOTB + 8192);
    }
    asm volatile("s_waitcnt vmcnt(8)" ::: "memory");
    __builtin_amdgcn_sched_barrier(0);
    __builtin_amdgcn_s_barrier();

    #pragma unroll 1
    for (int t = 0; t < NT; ++t) {
        const char* sp = smem + (t & 3) * SLOTB;
        const int ss = ((t + 3) & 3) * SLOTB;
        const bool pre = (t + 3) < NT;
        bf16x8 aF[4], bF[4];

        // ---- phase 0: m0-3 x n0-3 ----
        #pragma unroll
        for (int m = 0; m < 4; ++m) aF[m] = *(const bf16x8*)(sp + Aoff + m * 1024);
        #pragma unroll
        for (int n = 0; n < 4; ++n) bF[n] = *(const bf16x8*)(sp + Boff + n * 1024);
        if (pre) {
            STG(aP[0] + (t + 3) * 32, stA + ss);
            STG(aP[1] + (t + 3) * 32, stA + ss + 8192);
        }
        __builtin_amdgcn_s_barrier();
        asm volatile("s_waitcnt lgkmcnt(0)" ::: "memory");
        __builtin_amdgcn_sched_barrier(0);
        __builtin_amdgcn_s_setprio(1);
        #pragma unroll
        for (int m = 0; m < 4; ++m)
            #pragma unroll
            for (int n = 0; n < 4; ++n)
                acc[m][n] = __builtin_amdgcn_mfma_f32_16x16x32_bf16(aF[m], bF[n], acc[m][n], 0, 0, 0);
        __builtin_amdgcn_s_setprio(0);
        __builtin_amdgcn_s_barrier();

        // ---- phase 1: m4-7 x n0-3 (bF reused) ----
        #pragma unroll
        for (int m = 0; m < 4; ++m) aF[m] = *(const bf16x8*)(sp + Aoff + (m + 4) * 1024);
        if (pre) {
            STG(bP[0] + (t + 3) * 32, stB + ss);
            STG(bP[1] + (t + 3) * 32, stB + ss + 8192);
        }
        __builtin_amdgcn_s_barrier();
        asm volatile("s_waitcnt lgkmcnt(0)" ::: "memory");
        __builtin_amdgcn_sched_barrier(0);
        __builtin_amdgcn_s_setprio(1);
        #pragma unroll
        for (int m = 0; m < 4; ++m)
            #pragma unroll
            for (int n = 0; n < 4; ++n)
                acc[4 + m][n] = __builtin_amdgcn_mfma_f32_16x16x32_bf16(aF[m], bF[n], acc[4 + m][n], 0, 0, 0);
        __builtin_amdgcn_s_setprio(0);
        if (t < NT - 3)       { asm volatile("s_waitcnt vmcnt(8)" ::: "memory"); }
        else if (t == NT - 3) { asm volatile("s_waitcnt vmcnt(4)" ::: "memory"); }
        else if (t == NT - 2) { asm volatile("s_waitcnt vmcnt(0)" ::: "memory"); }
        __builtin_amdgcn_sched_barrier(0);
        __builtin_amdgcn_s_barrier();
    }

    // epilogue: r = wr*128 + m*16 + (lane>>4)*4 + i, c = wc*64 + n*16 + (lane&15)
    #pragma unroll
    for (int m = 0; m < 8; ++m) {
        #pragma unroll
        for (int i = 0; i < 4; ++i) {
            int r  = wr * 128 + m * 16 + (lane >> 4) * 4 + i;
            int rr = base + r;
            if (rr < cnt) {
                if constexpr (UP) {
                    uint16_t* hr = hid_out + (size_t)(cofs + rr) * DFF + bn0 + wc * 64;
                    #pragma unroll
                    for (int n = 0; n < 4; ++n) {
                        float v = acc[m][n][i];
                        v = v > 0.f ? v : 0.f;
                        hr[n * 16 + (lane & 15)] = f2bf(v);
                    }
                } else {
                    float* orow = out + (size_t)permE[rr] * DMODEL + bn0 + wc * 64;
                    #pragma unroll
                    for (int n = 0; n < 4; ++n)
                        orow[n * 16 + (lane & 15)] = acc[m][n][i];
                }
            }
        }
    }
}

extern "C" void kernel_launch(void* const* d_in, const int* in_sizes, int n_in,
                              void* d_out, int out_size, void* d_ws, size_t ws_size,
                              hipStream_t stream) {
    const float* x     = (const float*)d_in[0];
    const float* Wup   = (const float*)d_in[1];
    const float* Wdown = (const float*)d_in[2];
    float* out  = (float*)d_out;
    float* gate = out + (size_t)NTOK * DMODEL;

    char* ws = (char*)d_ws;
    size_t off = 0;
    auto alloc = [&](size_t bytes) -> void* {
        void* p = ws + off;
        off += (bytes + 255) & ~(size_t)255;
        return p;
    };
    int*      counts  = (int*)alloc(NTILES * sizeof(int));
    float*    sig     = (float*)alloc((size_t)NTILES * DMODEL * sizeof(float));
    double*   partial = (double*)alloc((size_t)NTILES * DMODEL * 256 * sizeof(double));
    int*      perm    = (int*)alloc((size_t)NTILES * NTOK * sizeof(int));
    uint16_t* xb      = (uint16_t*)alloc((size_t)NTOK * DMODEL * 2);
    uint16_t* wupb    = (uint16_t*)alloc((size_t)NTILES * DFF * DMODEL * 2);
    uint16_t* wdownb  = (uint16_t*)alloc((size_t)NTILES * DMODEL * DFF * 2);
    uint16_t* hidden  = (uint16_t*)alloc(((size_t)NTOK + 1024) * DFF * 2);
    if (off > ws_size) return;

    hipFuncSetAttribute((const void*)&k_ffn6<DMODEL, true>,
                        hipFuncAttributeMaxDynamicSharedMemorySize, 4 * SLOTB);
    hipFuncSetAttribute((const void*)&k_ffn6<DFF, false>,
                        hipFuncAttributeMaxDynamicSharedMemorySize, 4 * SLOTB);

    hipLaunchKernelGGL(k_convup, dim3(256, 4), dim3(256), 0, stream, Wup, wupb, partial);
    hipLaunchKernelGGL(k_sig_final, dim3(512), dim3(256), 0, stream, partial, sig, counts);
    hipLaunchKernelGGL(k_route, dim3(NTOK / 4), dim3(256), 0, stream,
                       x, sig, xb, gate, counts, perm);
    hipLaunchKernelGGL(k_conv, dim3(2048), dim3(256), 0, stream,
                       Wdown, wdownb, NTILES * DMODEL * DFF / 4);
    hipLaunchKernelGGL((k_ffn6<DMODEL, true>), dim3(DFF / 256, MAXJOBS, 1),
                       dim3(512), 4 * SLOTB, stream, xb, wupb, counts, perm, hidden, nullptr);
    hipLaunchKernelGGL((k_ffn6<DFF, false>), dim3(DMODEL / 256, MAXJOBS, 1),
                       dim3(512), 4 * SLOTB, stream, hidden, wdownb, counts, perm, nullptr, out);
}